// Round 15
// baseline (1826.715 us; speedup 1.0000x reference)
//
#include <hip/hip_runtime.h>
#include <hip/hip_bf16.h>
#include <math.h>

// ---------------------------------------------------------------------------
// 2-layer tanh RNN, B=64 S=512 I=256 H=512, fp32 in/out, bf16 MFMA compute.
// Round 15: R14 skeleton (k-split, 2 waves/SIMD, 1405 us fused) pushed to
// 4 WAVES/SIMD via k-split x4. 1024-thread blocks, launch_bounds(1024,1)
// -> 128 unified regs/wave. Per-wave: 4 k-tiles x 3 matrices = 12 frags =
// 48 AGPR (pinned), ~75 VGPR working set, 12 MFMAs. 4-way cross-quarter
// reduction via padded LDS (red[3][256][5], stride 5 = conflict-free).
// wk=0 waves finalize L0 (+pre), wk=1 finalize L1 (+bias).
// R12->R14 calibration: each waves/SIMD doubling recovered ~800 cy/iter of
// exposed latency; this round tests the third doubling.
// ALSO FIXED: h-state zero-init covered only slot 0 in R12-R14 (h1[1] was
// read uninitialized at i=1 and passed by luck) -- now zeroes both slots.
//
// Iteration i (0..512), sl=i&1, slw=sl^1 (R14 discipline):
//   A: wave1 lanes0-6 poll merged flags >= i; barrier; inv_l1
//   B: partner hex loads slot sl (1 uintx4/layer/thread); pv (wk0, i<=511)
//   early: wk0 waves, own k-tiles j=0,1
//   D: commit partner data -> h0[sl]/h1[sl]; barrier
//   main: wk0 j=2,3; wk1..3 j=0..3   (12 MFMAs/wave total incl. early)
//   R: wk!=0 write acc0p partials, wk!=1 write acc1p partials; barrier
//   E (wk0, i<=511): tanh(acc0p+Σred0+pv) -> h0[slw] + hex0[slw]
//   F (wk1, i>=1):   tanh(acc1p+Σred1+b1v) -> h1[slw] + hex1[slw]
//   barrier (drains vmcnt); tid0 relaxed-posts flags[lblk]=i+1
//
// ws layout (bytes): unchanged.
//   [0) Wp_hh0 512K | [524288) Wp_hh1 512K | [1048576) Wp_ih1 512K |
//   [1572864) Wp_ih0 256K | [1835008) hex 256K | [2097152) xb 16M |
//   [18874368) flags u32[256 zeroed, 32 used] | [52428800) pre 64M
// ---------------------------------------------------------------------------

typedef __attribute__((ext_vector_type(8))) short  short8;
typedef __attribute__((ext_vector_type(4))) float  floatx4;
typedef __attribute__((ext_vector_type(4))) unsigned int uintx4;

#define MFMA_BF16(a, b, c) __builtin_amdgcn_mfma_f32_16x16x32_bf16((a), (b), (c), 0, 0, 0)

// offsets in u16 units for bf16 regions
#define OFS_HH0   ((size_t)0)
#define OFS_HH1   ((size_t)262144)
#define OFS_IH1   ((size_t)524288)
#define OFS_IH0   ((size_t)786432)
#define OFS_XB    ((size_t)1048576)
#define HEX_BYTE   ((size_t)1835008)
#define FLAGS_BYTE ((size_t)18874368)
#define PRE_B      ((size_t)52428800)

__device__ __forceinline__ unsigned short f2bf(float f) {
    unsigned u = __builtin_bit_cast(unsigned, f);
    u += 0x7fffu + ((u >> 16) & 1u);          // round-to-nearest-even
    return (unsigned short)(u >> 16);
}
__device__ __forceinline__ float bf2f(unsigned short h) {
    return __builtin_bit_cast(float, ((unsigned)h) << 16);
}
__device__ __forceinline__ float fast_tanh(float x) {
    float z = fminf(9.0f, fmaxf(-9.0f, x));
    float e = __builtin_amdgcn_exp2f(z * 2.88539008f);   // e^{2z}
    return (e - 1.0f) * __builtin_amdgcn_rcpf(e + 1.0f);
}
// L1-only invalidate (vector L1 of this CU). Cheap; does NOT touch L2.
__device__ __forceinline__ void inv_l1() {
    asm volatile("buffer_inv sc0" ::: "memory");
}

// ---- prep: pack weights into MFMA B-fragment order + convert x + flags ----
__device__ __forceinline__ void pack_w(const float* __restrict__ W,
                                       unsigned short* __restrict__ Wp,
                                       int KT, int idx) {
    int l  = idx & 63;
    int kt = (idx >> 6) % KT;
    int nt = (idx >> 6) / KT;
    int Kdim = KT * 32;
    int row = nt * 16 + (l & 15);
    int col = kt * 32 + (l >> 4) * 8;
    const float* s = W + (size_t)row * Kdim + col;
    short8 v;
#pragma unroll
    for (int j = 0; j < 8; ++j) v[j] = (short)f2bf(s[j]);
    *(short8*)(Wp + (size_t)idx * 8) = v;
}

__global__ void prep_kernel(const float* __restrict__ x,
                            const float* __restrict__ whh0,
                            const float* __restrict__ whh1,
                            const float* __restrict__ wih1,
                            const float* __restrict__ wih0,
                            unsigned short* __restrict__ wsb) {
    int blk = blockIdx.x, tid = threadIdx.x;
    if (blk < 128) {
        pack_w(whh0, wsb + OFS_HH0, 16, blk * 256 + tid);
    } else if (blk < 256) {
        pack_w(whh1, wsb + OFS_HH1, 16, (blk - 128) * 256 + tid);
    } else if (blk < 384) {
        pack_w(wih1, wsb + OFS_IH1, 16, (blk - 256) * 256 + tid);
    } else if (blk < 448) {
        pack_w(wih0, wsb + OFS_IH0, 8, (blk - 384) * 256 + tid);
    } else if (blk < 4544) {
        size_t e = ((size_t)(blk - 448) * 256 + tid) * 8;
        const float* s = x + e;
        short8 v;
#pragma unroll
        for (int j = 0; j < 8; ++j) v[j] = (short)f2bf(s[j]);
        *(short8*)(wsb + OFS_XB + e) = v;
    } else {
        ((unsigned int*)((char*)wsb + FLAGS_BYTE))[tid] = 0u;   // 256 u32
    }
}

// ---- proj: pre0 = xb @ W_ih0^T + b_ih0 + b_hh0 -> fp32, PACKED for fused --
// (layout targets threads 0..255 (wk=0 waves) of the fused kernel: unchanged)
__global__ __launch_bounds__(512) void proj_kernel(
        const unsigned short* __restrict__ A,
        const unsigned short* __restrict__ Wp,
        const float* __restrict__ bias1, const float* __restrict__ bias2,
        float* __restrict__ out, int KT) {
    int tid = threadIdx.x, blk = blockIdx.x;
    int w = tid >> 6, l = tid & 63, lm = l & 15, lq = l >> 4;
    int mg = w >> 1, nh = w & 1;
    int Kdim = KT * 32;
    int r0 = blk * 64 + mg * 16;

    floatx4 acc[16];
#pragma unroll
    for (int i = 0; i < 16; ++i) acc[i] = (floatx4)0.f;

    for (int kt = 0; kt < KT; ++kt) {
        short8 a = *(const short8*)(A + (size_t)(r0 + lm) * Kdim + kt * 32 + lq * 8);
#pragma unroll
        for (int i = 0; i < 16; ++i) {
            int ntg = nh * 16 + i;
            short8 b = *(const short8*)(Wp + (((size_t)ntg * KT + kt) * 64 + l) * 8);
            acc[i] = MFMA_BF16(a, b, acc[i]);
        }
    }
#pragma unroll
    for (int i = 0; i < 16; ++i) {
        int n = (nh * 16 + i) * 16 + lm;
        float bs = bias1[n] + bias2[n];
        int slice2 = n >> 6, w2 = (n >> 4) & 3, lm2 = n & 15;
#pragma unroll
        for (int r = 0; r < 4; ++r) {
            int row = r0 + lq * 4 + r;                  // row = b*512 + t
            int b = row >> 9, tt = row & 511;
            int g2 = b >> 4, br = b & 15;
            int lblk2 = g2 * 8 + slice2;
            int tid2 = w2 * 64 + (br >> 2) * 16 + lm2;
            size_t idx = (((size_t)tt * 32 + lblk2) * 256 + tid2) * 4 + (br & 3);
            out[idx] = acc[i][r] + bs;
        }
    }
}

// ---- fused 2-layer scan: 32 active blocks x 1024 threads, k-split x4 ----
// Physical grid 60; active iff (blk&7)<4. XCD = blk%8 (round-robin, m09)
// => g = blk&7, slice = blk>>3 puts all 8 slices of group g on XCD g.
__global__ __launch_bounds__(1024, 1) void fused_kernel(
        const float* __restrict__ pre,           // packed fp32 (layer-0 input proj)
        const unsigned short* __restrict__ Whh0, // packed bf16 KT=16
        const unsigned short* __restrict__ Whh1,
        const unsigned short* __restrict__ Wih1,
        unsigned int* __restrict__ hex,          // merged exchange, u32 col-pairs
        unsigned int* __restrict__ flags,        // [32] merged per-block
        const float* __restrict__ bih1, const float* __restrict__ bhh1,
        const float* __restrict__ wfc, const float* __restrict__ bfc,
        float* __restrict__ out) {
    const int pblk = blockIdx.x;
    if ((pblk & 7) >= 4) return;                 // 28 dead residues exit at once

    __shared__ unsigned short h0[2][16][512];       // 32 KB, XOR-swizzled chunks
    __shared__ unsigned short h1[2][16][512];       // 32 KB
    __shared__ float red0[3][256][5];               // acc0 partials (wk1..3 -> wk0)
    __shared__ float red1[3][256][5];               // acc1 partials (wk0,2,3 -> wk1)

    const int tid = threadIdx.x;
    const int w = tid >> 6, l = tid & 63, lm = l & 15, lq = l >> 4;
    const int wk = w >> 2, wn = w & 3;             // k-quarter, n-tile in slice
    const int g = pblk & 7, slice = pblk >> 3;     // XCD-local: XCD(blk)=blk%8=g
    const int lblk = g * 8 + slice;                // logical id for pre/flags
    const int ntg = slice * 4 + wn;           // global 16-col tile (0..31)
    const int ncol = ntg * 16 + lm;           // global col this thread produces
    const int s2 = slice * 2;                 // own k-tiles {s2, s2+1}
    const int rid = tid & 255;                // reduction row (wn*64 + l)

    // zero BOTH slots of h state (R12-R14 bug: only slot 0 was zeroed;
    // h1[1] was read uninitialized at i=1 and passed by luck)
    {
        uintx4* z0 = (uintx4*)&h0[0][0][0];
        uintx4* z1 = (uintx4*)&h1[0][0][0];
        for (int i = tid; i < 2048; i += 1024) { z0[i] = (uintx4)0u; z1[i] = (uintx4)0u; }
    }
    // Weights, PRE-ROTATED per k-quarter: W?[j] = k-tile (s2 + 4*wk + j)&15.
    // UNIFORM 3x4 frags = 48 AGPR static footprint for every wave (pinned).
    short8 WA[4], WB[4], WC[4];
#pragma unroll
    for (int j = 0; j < 4; ++j) {
        int kt = (s2 + wk * 4 + j) & 15;
        size_t src = (((size_t)ntg * 16 + kt) * 64 + l) * 8;
        WA[j] = *(const short8*)(Whh0 + src);
        WB[j] = *(const short8*)(Wih1 + src);
        WC[j] = *(const short8*)(Whh1 + src);
        asm volatile("" : "+a"(WA[j]), "+a"(WB[j]), "+a"(WC[j]));
    }
    const float b1v = bih1[ncol] + bhh1[ncol];

    // exchange constants: thread covers chunk cch at row rquad (1 row/layer)
    const int cch = tid & 63;
    const int rquad = tid >> 6;                    // 0..15
    const bool dl = (cch >> 3) != slice;           // partner chunks only
    const bool poller = (w == 1) && (l < 7);
    const int ps = (slice + 1 + l) & 7;            // partner slice, lanes 0..6
    const int mychunk = ncol >> 3;

    __syncthreads();

    for (int i = 0; i <= 512; ++i) {
        const int sl = i & 1, slw = sl ^ 1;

        // --- A: merged-flag poll (relaxed, L2 hits) ---
        if (poller && i >= 1) {
            unsigned int tgt = (unsigned int)i;
            while (__hip_atomic_load(&flags[g * 8 + ps],
                                     __ATOMIC_RELAXED, __HIP_MEMORY_SCOPE_AGENT) < tgt)
                ;
        }
        __syncthreads();
        inv_l1();

        // --- B: partner loads (slot sl, 1 uintx4/layer) + pv (wk0 waves) ---
        const bool ld0 = dl && (i >= 1);
        const bool ld1 = dl && (i >= 2);
        uintx4 v0, v1;
        if (ld0)
            v0 = ((const uintx4*)(hex + (size_t)((sl * 4 + g) * 2 + 0) * 4096))
                     [rquad * 64 + cch];
        if (ld1)
            v1 = ((const uintx4*)(hex + (size_t)((sl * 4 + g) * 2 + 1) * 4096))
                     [rquad * 64 + cch];
        floatx4 pv = (floatx4)0.f;
        if (wk == 0 && i <= 511)        // wk0 <=> tid<256: matches pre layout
            pv = *(const floatx4*)(pre + (((size_t)i * 32 + lblk) * 256 + tid) * 4);

        // --- early: wk0 waves, own k-tiles j=0,1 ---
        floatx4 acc0p = (floatx4)0.f, acc1p = (floatx4)0.f;
        if (wk == 0) {
#pragma unroll
            for (int j = 0; j < 2; ++j) {
                int kt = s2 + j;
                int ch = ((kt * 4 + lq) ^ (lm & 7)) << 3;
                short8 a = *(const short8*)&h0[sl][lm][ch];
                acc0p = MFMA_BF16(a, WA[j], acc0p);
                acc1p = MFMA_BF16(a, WB[j], acc1p);
                short8 a1 = *(const short8*)&h1[sl][lm][ch];
                acc1p = MFMA_BF16(a1, WC[j], acc1p);
            }
        }

        // --- D: commit partner data ---
        if (ld0) *(uintx4*)&h0[sl][rquad][(cch ^ (rquad & 7)) * 8] = v0;
        if (ld1) *(uintx4*)&h1[sl][rquad][(cch ^ (rquad & 7)) * 8] = v1;
        __syncthreads();

        // --- main: wk0 j=2,3; wk1..3 j=0..3 (literal W indices) ---
        if (wk == 0) {
#pragma unroll
            for (int j = 2; j < 4; ++j) {
                int kt = (s2 + j) & 15;
                int ch = ((kt * 4 + lq) ^ (lm & 7)) << 3;
                short8 a = *(const short8*)&h0[sl][lm][ch];
                acc0p = MFMA_BF16(a, WA[j], acc0p);
                acc1p = MFMA_BF16(a, WB[j], acc1p);
                short8 a1 = *(const short8*)&h1[sl][lm][ch];
                acc1p = MFMA_BF16(a1, WC[j], acc1p);
            }
        } else {
#pragma unroll
            for (int j = 0; j < 4; ++j) {
                int kt = (s2 + wk * 4 + j) & 15;
                int ch = ((kt * 4 + lq) ^ (lm & 7)) << 3;
                short8 a = *(const short8*)&h0[sl][lm][ch];
                acc0p = MFMA_BF16(a, WA[j], acc0p);
                acc1p = MFMA_BF16(a, WB[j], acc1p);
                short8 a1 = *(const short8*)&h1[sl][lm][ch];
                acc1p = MFMA_BF16(a1, WC[j], acc1p);
            }
        }

        // --- R: cross-quarter partial exchange (stride-5 pad, no conflicts) ---
        if (wk != 0) {
#pragma unroll
            for (int r = 0; r < 4; ++r) red0[wk - 1][rid][r] = acc0p[r];
        }
        if (wk != 1) {
            int ridx = (wk == 0) ? 0 : wk - 1;     // wk0->0, wk2->1, wk3->2
#pragma unroll
            for (int r = 0; r < 4; ++r) red1[ridx][rid][r] = acc1p[r];
        }
        __syncthreads();

        // --- E: wk0 waves finalize L0 step i -> h0[slw] + hex0[slw] ---
        if (wk == 0 && i <= 511) {
            unsigned int* exw = hex + (size_t)((slw * 4 + g) * 2 + 0) * 4096;
#pragma unroll
            for (int r = 0; r < 4; ++r) {
                int row = lq * 4 + r;
                float v = acc0p[r] + red0[0][rid][r] + red0[1][rid][r]
                          + red0[2][rid][r] + pv[r];
                unsigned int hb = f2bf(fast_tanh(v));
                unsigned int pk = hb | ((unsigned int)__shfl_xor((int)hb, 1) << 16);
                if (!(lm & 1)) {
                    *(unsigned int*)&h0[slw][row][((mychunk ^ (row & 7)) << 3) | (ncol & 7)] = pk;
                    exw[(size_t)row * 256 + (ncol >> 1)] = pk;
                }
            }
        }
        // --- F: wk1 waves finalize L1 step i-1 -> h1[slw] + hex1[slw] ---
        if (wk == 1 && i >= 1) {
            unsigned int* exw = hex + (size_t)((slw * 4 + g) * 2 + 1) * 4096;
#pragma unroll
            for (int r = 0; r < 4; ++r) {
                int row = lq * 4 + r;
                float v = acc1p[r] + red1[0][rid][r] + red1[1][rid][r]
                          + red1[2][rid][r] + b1v;
                unsigned int hb = f2bf(fast_tanh(v));
                unsigned int pk = hb | ((unsigned int)__shfl_xor((int)hb, 1) << 16);
                if (!(lm & 1)) {
                    *(unsigned int*)&h1[slw][row][((mychunk ^ (row & 7)) << 3) | (ncol & 7)] = pk;
                    exw[(size_t)row * 256 + (ncol >> 1)] = pk;
                }
            }
        }

        __syncthreads();   // drains all waves' vmcnt => hex data in L2 pre-post

        // --- post: merged flag, single writer, relaxed ---
        if (tid == 0)
            __hip_atomic_store(&flags[lblk], (unsigned int)(i + 1),
                               __ATOMIC_RELAXED, __HIP_MEMORY_SCOPE_AGENT);
    }

    // --- FC head: slice-0 blocks gather full h1 final state ---
    if (slice == 0) {
        if (poller) {   // final post value is 513
            while (__hip_atomic_load(&flags[g * 8 + ps],
                                     __ATOMIC_RELAXED, __HIP_MEMORY_SCOPE_AGENT) < 513u)
                ;
        }
        __syncthreads();
        inv_l1();
        if (dl) {    // final h1 lives in hex slot 1, layer 1
            uintx4 v = ((const uintx4*)(hex + (size_t)((1 * 4 + g) * 2 + 1) * 4096))
                           [rquad * 64 + cch];
            *(uintx4*)&h1[1][rquad][(cch ^ (rquad & 7)) * 8] = v;
        }
        __syncthreads();
        if (tid < 160) {
            int b = tid / 10, c = tid % 10;
            float s = bfc[c];
            for (int n = 0; n < 512; ++n) {
                unsigned short hb = h1[1][b][(((n >> 3) ^ (b & 7)) << 3) | (n & 7)];
                s += bf2f(hb) * wfc[c * 512 + n];
            }
            out[(size_t)(g * 16 + b) * 10 + c] = s;
        }
    }
}

extern "C" void kernel_launch(void* const* d_in, const int* in_sizes, int n_in,
                              void* d_out, int out_size, void* d_ws, size_t ws_size,
                              hipStream_t stream) {
    const float* x    = (const float*)d_in[0];
    const float* wih0 = (const float*)d_in[1];
    const float* whh0 = (const float*)d_in[2];
    const float* bih0 = (const float*)d_in[3];
    const float* bhh0 = (const float*)d_in[4];
    const float* wih1 = (const float*)d_in[5];
    const float* whh1 = (const float*)d_in[6];
    const float* bih1 = (const float*)d_in[7];
    const float* bhh1 = (const float*)d_in[8];
    const float* wfc  = (const float*)d_in[9];
    const float* bfc  = (const float*)d_in[10];
    float* out = (float*)d_out;

    unsigned short* wsb  = (unsigned short*)d_ws;
    unsigned short* xb   = wsb + OFS_XB;
    unsigned int* hex    = (unsigned int*)((char*)d_ws + HEX_BYTE);
    unsigned int* flags  = (unsigned int*)((char*)d_ws + FLAGS_BYTE);
    float* pre = (float*)((char*)d_ws + PRE_B);

    // 1. pack weights + convert x + zero flags
    prep_kernel<<<dim3(4545), dim3(256), 0, stream>>>(x, whh0, whh1, wih1, wih0, wsb);
    // 2. pre0 = x @ w_ih0^T + b_ih0 + b_hh0  (packed for fused kernel)
    proj_kernel<<<dim3(512), dim3(512), 0, stream>>>(xb, wsb + OFS_IH0, bih0, bhh0, pre, 8);
    // 3. fused 2-layer scan + FC head (grid 60: 32 active, XCD-local groups)
    fused_kernel<<<dim3(60), dim3(1024), 0, stream>>>(
        pre, wsb + OFS_HH0, wsb + OFS_HH1, wsb + OFS_IH1,
        hex, flags, bih1, bhh1, wfc, bfc, out);
}

// Round 16
// 1384.266 us; speedup vs baseline: 1.3196x; 1.3196x over previous
//
#include <hip/hip_runtime.h>
#include <hip/hip_bf16.h>
#include <math.h>

// ---------------------------------------------------------------------------
// 2-layer tanh RNN, B=64 S=512 I=256 H=512, fp32 in/out, bf16 MFMA compute.
// Round 16: R14 geometry (512 thr, 2 waves/SIMD k-split -- the measured TLP
// optimum: 1w=7.4k, 2w=6.6k, 4w=8.2k cy/iter) minus one barrier.
// Change vs R14: ALL waves poll the 7 partner flags themselves (lanes 0-6
// ballot loop + per-wave inv_l1), so the post-poll __syncthreads is gone:
// 3 barriers/iter instead of 4. Hazard audit: commit(i) writes partner cols
// of h[sl] -- prior-iter reads hit the other slot; red-array WAR and
// own-col early reads are ordered by the final barrier; every block posts
// before it can block -> deadlock-free by induction.
// Also keeps R15's fix: BOTH h slots zero-initialized.
//
// Iteration i (0..512), sl=i&1, slw=sl^1:
//   A: every wave: lanes0-6 ballot-poll flags >= i; inv_l1
//   B: partner hex loads slot sl (L0 if i>=1, L1 if i>=2); pv (lower, i<=511)
//   early: lower waves j=0,1 (own k-tiles)
//   D: commit partner data -> h0[sl]/h1[sl]; barrier
//   main: lower j=2..7, upper j=0..7
//   R: lower writes acc1 partials, upper writes acc0 partials -> LDS; barrier
//   E (lower, i<=511): tanh(acc0p+red0+pv) -> h0[slw] + hex0[slw]
//   F (upper, i>=1):   tanh(accA+accB+red1+b1v) -> h1[slw] + hex1[slw]
//   barrier (drains vmcnt); tid0 relaxed-posts flags[lblk]=i+1
//
// ws layout (bytes): unchanged.
//   [0) Wp_hh0 512K | [524288) Wp_hh1 512K | [1048576) Wp_ih1 512K |
//   [1572864) Wp_ih0 256K | [1835008) hex 256K | [2097152) xb 16M |
//   [18874368) flags u32[256 zeroed, 32 used] | [52428800) pre 64M
// ---------------------------------------------------------------------------

typedef __attribute__((ext_vector_type(8))) short  short8;
typedef __attribute__((ext_vector_type(4))) float  floatx4;
typedef __attribute__((ext_vector_type(4))) unsigned int uintx4;

#define MFMA_BF16(a, b, c) __builtin_amdgcn_mfma_f32_16x16x32_bf16((a), (b), (c), 0, 0, 0)

// offsets in u16 units for bf16 regions
#define OFS_HH0   ((size_t)0)
#define OFS_HH1   ((size_t)262144)
#define OFS_IH1   ((size_t)524288)
#define OFS_IH0   ((size_t)786432)
#define OFS_XB    ((size_t)1048576)
#define HEX_BYTE   ((size_t)1835008)
#define FLAGS_BYTE ((size_t)18874368)
#define PRE_B      ((size_t)52428800)

__device__ __forceinline__ unsigned short f2bf(float f) {
    unsigned u = __builtin_bit_cast(unsigned, f);
    u += 0x7fffu + ((u >> 16) & 1u);          // round-to-nearest-even
    return (unsigned short)(u >> 16);
}
__device__ __forceinline__ float bf2f(unsigned short h) {
    return __builtin_bit_cast(float, ((unsigned)h) << 16);
}
__device__ __forceinline__ float fast_tanh(float x) {
    float z = fminf(9.0f, fmaxf(-9.0f, x));
    float e = __builtin_amdgcn_exp2f(z * 2.88539008f);   // e^{2z}
    return (e - 1.0f) * __builtin_amdgcn_rcpf(e + 1.0f);
}
// L1-only invalidate (vector L1 of this CU). Cheap; does NOT touch L2.
__device__ __forceinline__ void inv_l1() {
    asm volatile("buffer_inv sc0" ::: "memory");
}

// ---- prep: pack weights into MFMA B-fragment order + convert x + flags ----
__device__ __forceinline__ void pack_w(const float* __restrict__ W,
                                       unsigned short* __restrict__ Wp,
                                       int KT, int idx) {
    int l  = idx & 63;
    int kt = (idx >> 6) % KT;
    int nt = (idx >> 6) / KT;
    int Kdim = KT * 32;
    int row = nt * 16 + (l & 15);
    int col = kt * 32 + (l >> 4) * 8;
    const float* s = W + (size_t)row * Kdim + col;
    short8 v;
#pragma unroll
    for (int j = 0; j < 8; ++j) v[j] = (short)f2bf(s[j]);
    *(short8*)(Wp + (size_t)idx * 8) = v;
}

__global__ void prep_kernel(const float* __restrict__ x,
                            const float* __restrict__ whh0,
                            const float* __restrict__ whh1,
                            const float* __restrict__ wih1,
                            const float* __restrict__ wih0,
                            unsigned short* __restrict__ wsb) {
    int blk = blockIdx.x, tid = threadIdx.x;
    if (blk < 128) {
        pack_w(whh0, wsb + OFS_HH0, 16, blk * 256 + tid);
    } else if (blk < 256) {
        pack_w(whh1, wsb + OFS_HH1, 16, (blk - 128) * 256 + tid);
    } else if (blk < 384) {
        pack_w(wih1, wsb + OFS_IH1, 16, (blk - 256) * 256 + tid);
    } else if (blk < 448) {
        pack_w(wih0, wsb + OFS_IH0, 8, (blk - 384) * 256 + tid);
    } else if (blk < 4544) {
        size_t e = ((size_t)(blk - 448) * 256 + tid) * 8;
        const float* s = x + e;
        short8 v;
#pragma unroll
        for (int j = 0; j < 8; ++j) v[j] = (short)f2bf(s[j]);
        *(short8*)(wsb + OFS_XB + e) = v;
    } else {
        ((unsigned int*)((char*)wsb + FLAGS_BYTE))[tid] = 0u;   // 256 u32
    }
}

// ---- proj: pre0 = xb @ W_ih0^T + b_ih0 + b_hh0 -> fp32, PACKED for fused --
// (layout targets the LOWER 256 threads of the fused kernel: unchanged)
__global__ __launch_bounds__(512) void proj_kernel(
        const unsigned short* __restrict__ A,
        const unsigned short* __restrict__ Wp,
        const float* __restrict__ bias1, const float* __restrict__ bias2,
        float* __restrict__ out, int KT) {
    int tid = threadIdx.x, blk = blockIdx.x;
    int w = tid >> 6, l = tid & 63, lm = l & 15, lq = l >> 4;
    int mg = w >> 1, nh = w & 1;
    int Kdim = KT * 32;
    int r0 = blk * 64 + mg * 16;

    floatx4 acc[16];
#pragma unroll
    for (int i = 0; i < 16; ++i) acc[i] = (floatx4)0.f;

    for (int kt = 0; kt < KT; ++kt) {
        short8 a = *(const short8*)(A + (size_t)(r0 + lm) * Kdim + kt * 32 + lq * 8);
#pragma unroll
        for (int i = 0; i < 16; ++i) {
            int ntg = nh * 16 + i;
            short8 b = *(const short8*)(Wp + (((size_t)ntg * KT + kt) * 64 + l) * 8);
            acc[i] = MFMA_BF16(a, b, acc[i]);
        }
    }
#pragma unroll
    for (int i = 0; i < 16; ++i) {
        int n = (nh * 16 + i) * 16 + lm;
        float bs = bias1[n] + bias2[n];
        int slice2 = n >> 6, w2 = (n >> 4) & 3, lm2 = n & 15;
#pragma unroll
        for (int r = 0; r < 4; ++r) {
            int row = r0 + lq * 4 + r;                  // row = b*512 + t
            int b = row >> 9, tt = row & 511;
            int g2 = b >> 4, br = b & 15;
            int lblk2 = g2 * 8 + slice2;
            int tid2 = w2 * 64 + (br >> 2) * 16 + lm2;
            size_t idx = (((size_t)tt * 32 + lblk2) * 256 + tid2) * 4 + (br & 3);
            out[idx] = acc[i][r] + bs;
        }
    }
}

// ---- fused 2-layer scan: 32 active blocks x 512 threads, k-split --------
// Physical grid 60; active iff (blk&7)<4. XCD = blk%8 (round-robin, m09)
// => g = blk&7, slice = blk>>3 puts all 8 slices of group g on XCD g.
__global__ __launch_bounds__(512, 2) void fused_kernel(
        const float* __restrict__ pre,           // packed fp32 (layer-0 input proj)
        const unsigned short* __restrict__ Whh0, // packed bf16 KT=16
        const unsigned short* __restrict__ Whh1,
        const unsigned short* __restrict__ Wih1,
        unsigned int* __restrict__ hex,          // merged exchange, u32 col-pairs
        unsigned int* __restrict__ flags,        // [32] merged per-block
        const float* __restrict__ bih1, const float* __restrict__ bhh1,
        const float* __restrict__ wfc, const float* __restrict__ bfc,
        float* __restrict__ out) {
    const int pblk = blockIdx.x;
    if ((pblk & 7) >= 4) return;                 // 28 dead residues exit at once

    __shared__ unsigned short h0[2][16][512];       // 32 KB, XOR-swizzled chunks
    __shared__ unsigned short h1[2][16][512];       // 32 KB
    __shared__ float red0[256][5];                  // acc0 partials (upper->lower)
    __shared__ float red1[256][5];                  // acc1 partials (lower->upper)

    const int tid = threadIdx.x;
    const int w = tid >> 6, l = tid & 63, lm = l & 15, lq = l >> 4;
    const int wk = w >> 2, wn = w & 3;             // k-half, n-tile within slice
    const int g = pblk & 7, slice = pblk >> 3;     // XCD-local: XCD(blk)=blk%8=g
    const int lblk = g * 8 + slice;                // logical id for pre/flags
    const int ntg = slice * 4 + wn;           // global 16-col tile (0..31)
    const int ncol = ntg * 16 + lm;           // global col this thread produces
    const int s2 = slice * 2;                 // own k-tiles {s2, s2+1}
    const int rid = tid & 255;                // reduction partner index

    // zero BOTH slots of h state (R12-R14 bug fixed in R15: keep the fix)
    {
        uintx4* z0 = (uintx4*)&h0[0][0][0];
        uintx4* z1 = (uintx4*)&h1[0][0][0];
        for (int i = tid; i < 2048; i += 512) { z0[i] = (uintx4)0u; z1[i] = (uintx4)0u; }
    }
    // Weights, PRE-ROTATED per k-half: W?[j] = k-tile (s2 + 8*wk + j)&15.
    // UNIFORM 3x8 frags = 96 AGPR static footprint for every wave (pinned).
    short8 WA[8], WB[8], WC[8];
#pragma unroll
    for (int j = 0; j < 8; ++j) {
        int kt = (s2 + wk * 8 + j) & 15;
        size_t src = (((size_t)ntg * 16 + kt) * 64 + l) * 8;
        WA[j] = *(const short8*)(Whh0 + src);
        WB[j] = *(const short8*)(Wih1 + src);
        WC[j] = *(const short8*)(Whh1 + src);
        asm volatile("" : "+a"(WA[j]), "+a"(WB[j]), "+a"(WC[j]));
    }
    const float b1v = bih1[ncol] + bhh1[ncol];

    // exchange constants: thread covers chunk cch at rows rbase, rbase+8
    const int cch = tid & 63;
    const int rbase = tid >> 6;                    // 0..7
    const bool dl = (cch >> 3) != slice;           // partner chunks only
    const bool plane = (l < 7);                    // poll lanes (every wave)
    const int ps = (slice + 1 + l) & 7;            // partner slice, lanes 0..6
    const unsigned int* pf = flags + (plane ? (g * 8 + ps) : (g * 8));
    const int mychunk = ncol >> 3;

    __syncthreads();

    for (int i = 0; i <= 512; ++i) {
        const int sl = i & 1, slw = sl ^ 1;

        // --- A: EVERY wave ballot-polls its 7 partner flags (no barrier) ---
        if (i >= 1) {
            unsigned int tgt = (unsigned int)i;
            while (__ballot(plane && (__hip_atomic_load(pf, __ATOMIC_RELAXED,
                        __HIP_MEMORY_SCOPE_AGENT) < tgt)) != 0ULL) {}
        }
        inv_l1();

        // --- B: partner loads (slot sl) + pv (lower waves) ---
        const bool ld0 = dl && (i >= 1);
        const bool ld1 = dl && (i >= 2);
        uintx4 v00, v01, v10, v11;
        if (ld0) {
            const uintx4* s = (const uintx4*)(hex + (size_t)((sl * 4 + g) * 2 + 0) * 4096);
            v00 = s[rbase * 64 + cch];
            v01 = s[(rbase + 8) * 64 + cch];
        }
        if (ld1) {
            const uintx4* s = (const uintx4*)(hex + (size_t)((sl * 4 + g) * 2 + 1) * 4096);
            v10 = s[rbase * 64 + cch];
            v11 = s[(rbase + 8) * 64 + cch];
        }
        floatx4 pv = (floatx4)0.f;
        if (wk == 0 && i <= 511)
            pv = *(const floatx4*)(pre + (((size_t)i * 32 + lblk) * 256 + tid) * 4);

        // --- early: lower waves, own k-tiles j=0,1 ---
        floatx4 acc0p = (floatx4)0.f, accA = (floatx4)0.f, accB = (floatx4)0.f;
        if (wk == 0) {
#pragma unroll
            for (int j = 0; j < 2; ++j) {
                int kt = s2 + j;
                int ch = ((kt * 4 + lq) ^ (lm & 7)) << 3;
                short8 a = *(const short8*)&h0[sl][lm][ch];
                acc0p = MFMA_BF16(a, WA[j], acc0p);
                accA  = MFMA_BF16(a, WB[j], accA);
                short8 a1 = *(const short8*)&h1[sl][lm][ch];
                accB  = MFMA_BF16(a1, WC[j], accB);
            }
        }

        // --- D: commit partner data ---
        if (ld0) {
            int r0r = rbase, r1r = rbase + 8;
            *(uintx4*)&h0[sl][r0r][(cch ^ (r0r & 7)) * 8] = v00;
            *(uintx4*)&h0[sl][r1r][(cch ^ (r1r & 7)) * 8] = v01;
        }
        if (ld1) {
            int r0r = rbase, r1r = rbase + 8;
            *(uintx4*)&h1[sl][r0r][(cch ^ (r0r & 7)) * 8] = v10;
            *(uintx4*)&h1[sl][r1r][(cch ^ (r1r & 7)) * 8] = v11;
        }
        __syncthreads();                           // barrier 1 of 3

        // --- main: lower j=2..7, upper j=0..7 (literal W indices) ---
        if (wk == 0) {
#pragma unroll
            for (int j = 2; j < 8; ++j) {
                int kt = (s2 + j) & 15;
                int ch = ((kt * 4 + lq) ^ (lm & 7)) << 3;
                short8 a = *(const short8*)&h0[sl][lm][ch];
                acc0p = MFMA_BF16(a, WA[j], acc0p);
                accA  = MFMA_BF16(a, WB[j], accA);
                short8 a1 = *(const short8*)&h1[sl][lm][ch];
                accB  = MFMA_BF16(a1, WC[j], accB);
            }
        } else {
#pragma unroll
            for (int j = 0; j < 8; ++j) {
                int kt = (s2 + 8 + j) & 15;
                int ch = ((kt * 4 + lq) ^ (lm & 7)) << 3;
                short8 a = *(const short8*)&h0[sl][lm][ch];
                acc0p = MFMA_BF16(a, WA[j], acc0p);
                accA  = MFMA_BF16(a, WB[j], accA);
                short8 a1 = *(const short8*)&h1[sl][lm][ch];
                accB  = MFMA_BF16(a1, WC[j], accB);
            }
        }

        // --- R: cross-half partial exchange (padded LDS, conflict-free) ---
        if (wk == 0) {
#pragma unroll
            for (int r = 0; r < 4; ++r) red1[rid][r] = accA[r] + accB[r];
        } else {
#pragma unroll
            for (int r = 0; r < 4; ++r) red0[rid][r] = acc0p[r];
        }
        __syncthreads();                           // barrier 2 of 3

        // --- E: lower waves finalize L0 step i -> h0[slw] + hex0[slw] ---
        if (wk == 0 && i <= 511) {
            unsigned int* exw = hex + (size_t)((slw * 4 + g) * 2 + 0) * 4096;
#pragma unroll
            for (int r = 0; r < 4; ++r) {
                int row = lq * 4 + r;
                unsigned int hb = f2bf(fast_tanh(acc0p[r] + red0[rid][r] + pv[r]));
                unsigned int pk = hb | ((unsigned int)__shfl_xor((int)hb, 1) << 16);
                if (!(lm & 1)) {
                    *(unsigned int*)&h0[slw][row][((mychunk ^ (row & 7)) << 3) | (ncol & 7)] = pk;
                    exw[(size_t)row * 256 + (ncol >> 1)] = pk;
                }
            }
        }
        // --- F: upper waves finalize L1 step i-1 -> h1[slw] + hex1[slw] ---
        if (wk == 1 && i >= 1) {
            unsigned int* exw = hex + (size_t)((slw * 4 + g) * 2 + 1) * 4096;
#pragma unroll
            for (int r = 0; r < 4; ++r) {
                int row = lq * 4 + r;
                unsigned int hb =
                    f2bf(fast_tanh(accA[r] + accB[r] + red1[rid][r] + b1v));
                unsigned int pk = hb | ((unsigned int)__shfl_xor((int)hb, 1) << 16);
                if (!(lm & 1)) {
                    *(unsigned int*)&h1[slw][row][((mychunk ^ (row & 7)) << 3) | (ncol & 7)] = pk;
                    exw[(size_t)row * 256 + (ncol >> 1)] = pk;
                }
            }
        }

        __syncthreads();                           // barrier 3 of 3 (vmcnt drain)

        // --- post: merged flag, single writer, relaxed ---
        if (tid == 0)
            __hip_atomic_store(&flags[lblk], (unsigned int)(i + 1),
                               __ATOMIC_RELAXED, __HIP_MEMORY_SCOPE_AGENT);
    }

    // --- FC head: slice-0 blocks gather full h1 final state ---
    if (slice == 0) {
        if (plane && w == 1) {   // final post value is 513
            while (__hip_atomic_load(&flags[g * 8 + ps],
                                     __ATOMIC_RELAXED, __HIP_MEMORY_SCOPE_AGENT) < 513u)
                ;
        }
        __syncthreads();
        inv_l1();
        if (dl) {    // final h1 lives in hex slot 1, layer 1
            const uintx4* s = (const uintx4*)(hex + (size_t)((1 * 4 + g) * 2 + 1) * 4096);
            uintx4 a = s[rbase * 64 + cch];
            uintx4 b = s[(rbase + 8) * 64 + cch];
            int r0r = rbase, r1r = rbase + 8;
            *(uintx4*)&h1[1][r0r][(cch ^ (r0r & 7)) * 8] = a;
            *(uintx4*)&h1[1][r1r][(cch ^ (r1r & 7)) * 8] = b;
        }
        __syncthreads();
        if (tid < 160) {
            int b = tid / 10, c = tid % 10;
            float s = bfc[c];
            for (int n = 0; n < 512; ++n) {
                unsigned short hb = h1[1][b][(((n >> 3) ^ (b & 7)) << 3) | (n & 7)];
                s += bf2f(hb) * wfc[c * 512 + n];
            }
            out[(size_t)(g * 16 + b) * 10 + c] = s;
        }
    }
}

extern "C" void kernel_launch(void* const* d_in, const int* in_sizes, int n_in,
                              void* d_out, int out_size, void* d_ws, size_t ws_size,
                              hipStream_t stream) {
    const float* x    = (const float*)d_in[0];
    const float* wih0 = (const float*)d_in[1];
    const float* whh0 = (const float*)d_in[2];
    const float* bih0 = (const float*)d_in[3];
    const float* bhh0 = (const float*)d_in[4];
    const float* wih1 = (const float*)d_in[5];
    const float* whh1 = (const float*)d_in[6];
    const float* bih1 = (const float*)d_in[7];
    const float* bhh1 = (const float*)d_in[8];
    const float* wfc  = (const float*)d_in[9];
    const float* bfc  = (const float*)d_in[10];
    float* out = (float*)d_out;

    unsigned short* wsb  = (unsigned short*)d_ws;
    unsigned short* xb   = wsb + OFS_XB;
    unsigned int* hex    = (unsigned int*)((char*)d_ws + HEX_BYTE);
    unsigned int* flags  = (unsigned int*)((char*)d_ws + FLAGS_BYTE);
    float* pre = (float*)((char*)d_ws + PRE_B);

    // 1. pack weights + convert x + zero flags
    prep_kernel<<<dim3(4545), dim3(256), 0, stream>>>(x, whh0, whh1, wih1, wih0, wsb);
    // 2. pre0 = x @ w_ih0^T + b_ih0 + b_hh0  (packed for fused kernel)
    proj_kernel<<<dim3(512), dim3(512), 0, stream>>>(xb, wsb + OFS_IH0, bih0, bhh0, pre, 8);
    // 3. fused 2-layer scan + FC head (grid 60: 32 active, XCD-local groups)
    fused_kernel<<<dim3(60), dim3(512), 0, stream>>>(
        pre, wsb + OFS_HH0, wsb + OFS_HH1, wsb + OFS_IH1,
        hex, flags, bih1, bhh1, wfc, bfc, out);
}